// Round 1
// baseline (241.913 us; speedup 1.0000x reference)
//
#include <hip/hip_runtime.h>
#include <stdint.h>

typedef unsigned short u16;
typedef __attribute__((ext_vector_type(4))) float floatx4;
typedef __attribute__((ext_vector_type(8))) short bf16x8;

#define MTOK   32768   // 512 windows * 64 tokens
#define KDIM   512
#define NQKV   1536
#define NWIN   512
#define N_HEAD 16
#define QK_SCALE 0.17677669529663687f  // 32^-0.5

__device__ __forceinline__ u16 f2bf(float f) {
  union { float f; unsigned u; } v; v.f = f;
  unsigned r = v.u + 0x7fffu + ((v.u >> 16) & 1u);
  return (u16)(r >> 16);
}

__device__ __forceinline__ void load_lds16(const void* g, void* l) {
  __builtin_amdgcn_global_load_lds((const __attribute__((address_space(1))) void*)g,
                                   (__attribute__((address_space(3))) void*)l,
                                   16, 0, 0);
}

// ---------------- kernel 1: x (8,64,64,512) fp32 -> A (32768,512) bf16, window order
__global__ __launch_bounds__(256) void convert_x(const float* __restrict__ x,
                                                 u16* __restrict__ A) {
  int idx = blockIdx.x * 256 + threadIdx.x;
  int e = idx * 4;                     // element index in A
  int c = e & 511;
  int tg = e >> 9;                     // global token (window-ordered)
  int w = tg >> 6, t = tg & 63;
  int img = w >> 6, wy = (w >> 3) & 7, wx = w & 7;
  int ty = t >> 3, tx = t & 7;
  int y = wy * 8 + ty, xp = wx * 8 + tx;
  const float4 v = *(const float4*)(x + (((img * 64 + y) * 64 + xp) * 512 + c));
  ushort4 o;
  o.x = f2bf(v.x); o.y = f2bf(v.y); o.z = f2bf(v.z); o.w = f2bf(v.w);
  *(ushort4*)(A + e) = o;
}

// ---------------- kernel 2: qkv_w (1536,512) fp32 -> bf16 (straight copy)
__global__ __launch_bounds__(256) void convert_w(const float* __restrict__ wsrc,
                                                 u16* __restrict__ Wb) {
  int e = (blockIdx.x * 256 + threadIdx.x) * 4;
  const float4 v = *(const float4*)(wsrc + e);
  ushort4 o;
  o.x = f2bf(v.x); o.y = f2bf(v.y); o.z = f2bf(v.z); o.w = f2bf(v.w);
  *(ushort4*)(Wb + e) = o;
}

// ---------------- kernel 3: QKV = A(32768x512) * Wb^T(1536x512) + bias, bf16 out
// m97 structure: 128x128 tile, BK=32, 4 waves, 4x4 16x16x32 MFMA frags/wave
__global__ __launch_bounds__(256) void gemm_qkv(const u16* __restrict__ A,
                                                const u16* __restrict__ Wb,
                                                const float* __restrict__ bias,
                                                u16* __restrict__ QKV) {
  __shared__ __attribute__((aligned(16))) u16 lA[128 * 32];
  __shared__ __attribute__((aligned(16))) u16 lB[128 * 32];

  // XCD swizzle: all 12 n-tiles of one m-tile on the same XCD (A stays in that L2)
  int b = blockIdx.x;
  int xcd = b & 7, slot = b >> 3;
  int mtile = (slot / 12) * 8 + xcd;   // [0,256)
  int ntile = slot % 12;               // [0,12)

  int tid = threadIdx.x;
  int wv = tid >> 6, lane = tid & 63;
  int il = lane & 15, ch = lane >> 4;
  int wm = (wv & 1) * 64, wn = (wv >> 1) * 64;

  floatx4 acc[4][4];
  floatx4 zacc = {0.f, 0.f, 0.f, 0.f};
#pragma unroll
  for (int m = 0; m < 4; ++m)
#pragma unroll
    for (int n = 0; n < 4; ++n) acc[m][n] = zacc;

  int row0 = tid >> 2, ch4 = tid & 3;
  const u16* Abase = A + (mtile * 128 + row0) * KDIM + ch4 * 8;
  const u16* Bbase = Wb + (ntile * 128 + row0) * KDIM + ch4 * 8;
  char* lAb = (char*)lA;
  char* lBb = (char*)lB;
  char* lA0 = lAb + wv * 1024;
  char* lA1 = lAb + 4096 + wv * 1024;
  char* lB0 = lBb + wv * 1024;
  char* lB1 = lBb + 4096 + wv * 1024;

  for (int kb = 0; kb < KDIM; kb += 32) {
    __syncthreads();                 // prev-iter LDS reads done
    load_lds16(Abase + kb, lA0);
    load_lds16(Abase + kb + 64 * KDIM, lA1);
    load_lds16(Bbase + kb, lB0);
    load_lds16(Bbase + kb + 64 * KDIM, lB1);
    __syncthreads();                 // staging complete (vmcnt drained)

    bf16x8 af[4], bfr[4];
#pragma unroll
    for (int mt = 0; mt < 4; ++mt)
      af[mt] = *(const bf16x8*)(lAb + (wm + mt * 16 + il) * 64 + ch * 16);
#pragma unroll
    for (int nt = 0; nt < 4; ++nt)
      bfr[nt] = *(const bf16x8*)(lBb + (wn + nt * 16 + il) * 64 + ch * 16);
#pragma unroll
    for (int mt = 0; mt < 4; ++mt)
#pragma unroll
      for (int nt = 0; nt < 4; ++nt)
        acc[mt][nt] = __builtin_amdgcn_mfma_f32_16x16x32_bf16(af[mt], bfr[nt], acc[mt][nt], 0, 0, 0);
  }

  // epilogue: + bias, bf16 convert, store. C/D layout: col=lane&15, row=(lane>>4)*4+reg
#pragma unroll
  for (int nt = 0; nt < 4; ++nt) {
    int col = ntile * 128 + wn + nt * 16 + il;
    float bv = bias[col];
#pragma unroll
    for (int mt = 0; mt < 4; ++mt) {
      int rbase = mtile * 128 + wm + mt * 16 + ch * 4;
#pragma unroll
      for (int r = 0; r < 4; ++r)
        QKV[(rbase + r) * NQKV + col] = f2bf(acc[mt][nt][r] + bv);
    }
  }
}

// ---------------- kernel 4: attention, one block = (window, head), 4 waves
__global__ __launch_bounds__(256) void attn(const u16* __restrict__ QKV,
                                            const float* __restrict__ btab,
                                            float* __restrict__ out) {
  __shared__ __attribute__((aligned(16))) u16 Pl[64 * 88];   // P, stride 88 (2-way banks, 16B rows)
  __shared__ __attribute__((aligned(16))) u16 Vt[32 * 88];   // V transposed [d][j]
  __shared__ float sbias[225];

  int bid = blockIdx.x;
  int w = bid >> 4, h = bid & 15;
  int tid = threadIdx.x;

  // stage V transposed: V[j][d] = QKV[w*64+j][1024 + h*32 + d]
  {
    int j = tid >> 2, dbase = (tid & 3) * 8;
    const u16* vp = QKV + (w * 64 + j) * NQKV + 1024 + h * 32 + dbase;
    union { uint4 v; u16 s[8]; } u;
    u.v = *(const uint4*)vp;
#pragma unroll
    for (int q = 0; q < 8; ++q) Vt[(dbase + q) * 88 + j] = u.s[q];
  }
  if (tid < 225) sbias[tid] = btab[tid * 16 + h];

  int lane = tid & 63, wv = tid >> 6;
  int il = lane & 15, ch = lane >> 4;
  const u16* qkw = QKV + (w * 64) * NQKV;

  // S = Q K^T : wave wv owns rows [wv*16, wv*16+16), K-dim 32 = one mfma step
  bf16x8 aq = *(const bf16x8*)(qkw + (wv * 16 + il) * NQKV + h * 32 + ch * 8);
  floatx4 zacc = {0.f, 0.f, 0.f, 0.f};
  floatx4 s[4];
#pragma unroll
  for (int jt = 0; jt < 4; ++jt) {
    bf16x8 bk = *(const bf16x8*)(qkw + (jt * 16 + il) * NQKV + 512 + h * 32 + ch * 8);
    s[jt] = __builtin_amdgcn_mfma_f32_16x16x32_bf16(aq, bk, zacc, 0, 0, 0);
  }

  __syncthreads();   // sbias + Vt visible

  // logits: scale + rel-pos bias + shift mask (inline), then softmax per row
  int winidx = w & 63;
  int wy = winidx >> 3, wx = winidx & 7;
  float val[4][4];
#pragma unroll
  for (int r = 0; r < 4; ++r) {
    int i = wv * 16 + ch * 4 + r;
    int ty = i >> 3, tx = i & 7;
    int ry = (wy == 7) ? (ty < 4 ? 1 : 2) : 0;
    int rx = (wx == 7) ? (tx < 4 ? 1 : 2) : 0;
    int li = ry * 3 + rx;
#pragma unroll
    for (int jt = 0; jt < 4; ++jt) {
      int j = jt * 16 + il;
      int sy = j >> 3, sx = j & 7;
      int rjy = (wy == 7) ? (sy < 4 ? 1 : 2) : 0;
      int rjx = (wx == 7) ? (sx < 4 ? 1 : 2) : 0;
      float v = s[jt][r] * QK_SCALE + sbias[(ty - sy + 7) * 15 + (tx - sx + 7)];
      if (li != (rjy * 3 + rjx)) v -= 100.0f;
      val[r][jt] = v;
    }
  }

#pragma unroll
  for (int r = 0; r < 4; ++r) {
    float m = fmaxf(fmaxf(val[r][0], val[r][1]), fmaxf(val[r][2], val[r][3]));
    m = fmaxf(m, __shfl_xor(m, 1, 64));
    m = fmaxf(m, __shfl_xor(m, 2, 64));
    m = fmaxf(m, __shfl_xor(m, 4, 64));
    m = fmaxf(m, __shfl_xor(m, 8, 64));
    float sum = 0.f;
#pragma unroll
    for (int jt = 0; jt < 4; ++jt) { val[r][jt] = __expf(val[r][jt] - m); sum += val[r][jt]; }
    sum += __shfl_xor(sum, 1, 64);
    sum += __shfl_xor(sum, 2, 64);
    sum += __shfl_xor(sum, 4, 64);
    sum += __shfl_xor(sum, 8, 64);
    float inv = 1.0f / sum;
    int i = wv * 16 + ch * 4 + r;
#pragma unroll
    for (int jt = 0; jt < 4; ++jt)
      Pl[i * 88 + jt * 16 + il] = f2bf(val[r][jt] * inv);
  }

  __syncthreads();   // P visible

  // O = P V : wave wv owns rows [wv*16,+16), 2 d-tiles, K-dim 64 = 2 steps
  floatx4 o0 = zacc, o1 = zacc;
#pragma unroll
  for (int kk = 0; kk < 2; ++kk) {
    bf16x8 ap  = *(const bf16x8*)((const u16*)Pl + (wv * 16 + il) * 88 + kk * 32 + ch * 8);
    bf16x8 bv0 = *(const bf16x8*)((const u16*)Vt + il * 88 + kk * 32 + ch * 8);
    bf16x8 bv1 = *(const bf16x8*)((const u16*)Vt + (16 + il) * 88 + kk * 32 + ch * 8);
    o0 = __builtin_amdgcn_mfma_f32_16x16x32_bf16(ap, bv0, o0, 0, 0, 0);
    o1 = __builtin_amdgcn_mfma_f32_16x16x32_bf16(ap, bv1, o1, 0, 0, 0);
  }

  // scatter to (n,H,W,C) fp32
  int img = w >> 6;
#pragma unroll
  for (int r = 0; r < 4; ++r) {
    int i = wv * 16 + ch * 4 + r;
    int ty = i >> 3, tx = i & 7;
    int y = wy * 8 + ty, xp = wx * 8 + tx;
    float* op = out + ((img * 64 + y) * 64 + xp) * 512 + h * 32;
    op[il] = o0[r];
    op[16 + il] = o1[r];
  }
}

extern "C" void kernel_launch(void* const* d_in, const int* in_sizes, int n_in,
                              void* d_out, int out_size, void* d_ws, size_t ws_size,
                              hipStream_t stream) {
  const float* x      = (const float*)d_in[0];
  const float* qkv_w  = (const float*)d_in[1];
  const float* qkv_b  = (const float*)d_in[2];
  const float* btab   = (const float*)d_in[3];
  float* out = (float*)d_out;

  char* ws = (char*)d_ws;
  u16* A   = (u16*)ws;                                              // 32 MB
  u16* Wb  = (u16*)(ws + (size_t)MTOK * KDIM * 2);                  // 1.5 MB
  u16* QKV = (u16*)(ws + (size_t)MTOK * KDIM * 2 + (size_t)NQKV * KDIM * 2);  // 96 MB

  convert_x<<<dim3(MTOK * KDIM / 1024), dim3(256), 0, stream>>>(x, A);
  convert_w<<<dim3(NQKV * KDIM / 1024), dim3(256), 0, stream>>>(qkv_w, Wb);
  gemm_qkv<<<dim3(3072), dim3(256), 0, stream>>>(A, Wb, qkv_b, QKV);
  attn<<<dim3(NWIN * N_HEAD), dim3(256), 0, stream>>>(QKV, btab, out);
}

// Round 3
// 239.631 us; speedup vs baseline: 1.0095x; 1.0095x over previous
//
#include <hip/hip_runtime.h>
#include <stdint.h>

typedef unsigned short u16;
typedef __attribute__((ext_vector_type(4))) float floatx4;
typedef __attribute__((ext_vector_type(8))) short bf16x8;

#define MTOK   32768   // 512 windows * 64 tokens
#define KDIM   512
#define NQKV   1536
#define NWIN   512
#define N_HEAD 16
#define SECSZ  (512 * 16 * 2048)   // u16 elems per Q/K/V section (32 MB)
#define QK_SCALE 0.17677669529663687f  // 32^-0.5

__device__ __forceinline__ u16 f2bf(float f) {
  union { float f; unsigned u; } v; v.f = f;
  unsigned r = v.u + 0x7fffu + ((v.u >> 16) & 1u);
  return (u16)(r >> 16);
}

__device__ __forceinline__ void load_lds16(const void* g, void* l) {
  __builtin_amdgcn_global_load_lds((const __attribute__((address_space(1))) void*)g,
                                   (__attribute__((address_space(3))) void*)l,
                                   16, 0, 0);
}

// ---------------- kernel 1: x (8,64,64,512) fp32 -> A (32768,512) bf16, window order
__global__ __launch_bounds__(256) void convert_x(const float* __restrict__ x,
                                                 u16* __restrict__ A) {
  int idx = blockIdx.x * 256 + threadIdx.x;
  int e = idx * 4;
  int c = e & 511;
  int tg = e >> 9;
  int w = tg >> 6, t = tg & 63;
  int img = w >> 6, wy = (w >> 3) & 7, wx = w & 7;
  int ty = t >> 3, tx = t & 7;
  int y = wy * 8 + ty, xp = wx * 8 + tx;
  const float4 v = *(const float4*)(x + (((img * 64 + y) * 64 + xp) * 512 + c));
  ushort4 o;
  o.x = f2bf(v.x); o.y = f2bf(v.y); o.z = f2bf(v.z); o.w = f2bf(v.w);
  *(ushort4*)(A + e) = o;
}

// ---------------- kernel 2: qkv_w (1536,512) fp32 -> bf16
__global__ __launch_bounds__(256) void convert_w(const float* __restrict__ wsrc,
                                                 u16* __restrict__ Wb) {
  int e = (blockIdx.x * 256 + threadIdx.x) * 4;
  const float4 v = *(const float4*)(wsrc + e);
  ushort4 o;
  o.x = f2bf(v.x); o.y = f2bf(v.y); o.z = f2bf(v.z); o.w = f2bf(v.w);
  *(ushort4*)(Wb + e) = o;
}

// ---------------- kernel 3: QKV GEMM, bias fused, Q pre-scaled, V transposed
// out layouts (bf16): Q/K: [w][h][t=64][d=32]  V: [w][h][d=32][t=64]
__global__ __launch_bounds__(256) void gemm_qkv(const u16* __restrict__ A,
                                                const u16* __restrict__ Wb,
                                                const float* __restrict__ bias,
                                                u16* __restrict__ QKV) {
  // smem: K-loop staging (lA 8KB + lB 8KB) OR epilogue tile 128x136 u16 (34 KB)
  __shared__ __attribute__((aligned(16))) char smem[34816];
  u16* Ct = (u16*)smem;

  int b = blockIdx.x;
  int xcd = b & 7, slot = b >> 3;
  int mtile = (slot / 12) * 8 + xcd;   // [0,256)
  int ntile = slot % 12;               // [0,12)

  int tid = threadIdx.x;
  int wv = tid >> 6, lane = tid & 63;
  int il = lane & 15, ch = lane >> 4;
  int wm = (wv & 1) * 64, wn = (wv >> 1) * 64;

  floatx4 acc[4][4];
  floatx4 zacc = {0.f, 0.f, 0.f, 0.f};
#pragma unroll
  for (int m = 0; m < 4; ++m)
#pragma unroll
    for (int n = 0; n < 4; ++n) acc[m][n] = zacc;

  // staging: LDS[row][p] = global[row][p ^ (row&3)]  (bank-conflict XOR swizzle)
  int row0 = tid >> 2;
  int ch4 = (tid & 3) ^ (row0 & 3);
  const u16* Abase = A + (mtile * 128 + row0) * KDIM + ch4 * 8;
  const u16* Bbase = Wb + (ntile * 128 + row0) * KDIM + ch4 * 8;
  char* lAb = smem;
  char* lBb = smem + 8192;
  char* lA0 = lAb + wv * 1024;
  char* lA1 = lAb + 4096 + wv * 1024;
  char* lB0 = lBb + wv * 1024;
  char* lB1 = lBb + 4096 + wv * 1024;

  int sw = il & 3;                     // frag-read swizzle: row&3 == il&3
  for (int kb = 0; kb < KDIM; kb += 32) {
    __syncthreads();
    load_lds16(Abase + kb, lA0);
    load_lds16(Abase + kb + 64 * KDIM, lA1);
    load_lds16(Bbase + kb, lB0);
    load_lds16(Bbase + kb + 64 * KDIM, lB1);
    __syncthreads();

    bf16x8 af[4], bfr[4];
#pragma unroll
    for (int mt = 0; mt < 4; ++mt)
      af[mt] = *(const bf16x8*)(lAb + (wm + mt * 16 + il) * 64 + (ch ^ sw) * 16);
#pragma unroll
    for (int nt = 0; nt < 4; ++nt)
      bfr[nt] = *(const bf16x8*)(lBb + (wn + nt * 16 + il) * 64 + (ch ^ sw) * 16);
#pragma unroll
    for (int mt = 0; mt < 4; ++mt)
#pragma unroll
      for (int nt = 0; nt < 4; ++nt)
        acc[mt][nt] = __builtin_amdgcn_mfma_f32_16x16x32_bf16(af[mt], bfr[nt], acc[mt][nt], 0, 0, 0);
  }

  __syncthreads();   // K-loop LDS reads done before smem reuse

  // epilogue: C/D layout col=lane&15, row=(lane>>4)*4+reg
  int sec = ntile >> 2;              // 0=Q 1=K 2=V
  int h0 = (ntile & 3) * 4;          // 4 heads per block
  int gw0 = mtile * 2;               // 2 windows per block
  u16* dst = QKV + (size_t)sec * SECSZ;

  if (sec < 2) {
    float sc = (sec == 0) ? QK_SCALE : 1.0f;
    // stage [t=128][c=128], row stride 136 u16 (272B, 16B aligned)
#pragma unroll
    for (int nt = 0; nt < 4; ++nt) {
      float bv = bias[ntile * 128 + wn + nt * 16 + il];
      int cl = wn + nt * 16 + il;
#pragma unroll
      for (int mt = 0; mt < 4; ++mt) {
        int T0 = wm + mt * 16 + ch * 4;
#pragma unroll
        for (int r = 0; r < 4; ++r)
          Ct[(T0 + r) * 136 + cl] = f2bf((acc[mt][nt][r] + bv) * sc);
      }
    }
    __syncthreads();
    int t_loc = tid >> 2, dc = tid & 3;
#pragma unroll
    for (int it = 0; it < 8; ++it) {
      int wl = it >> 2, hl = it & 3;
      uint4 v = *(const uint4*)(smem + (wl * 64 + t_loc) * 272 + hl * 64 + dc * 16);
      *(uint4*)(dst + ((gw0 + wl) * 16 + h0 + hl) * 2048 + t_loc * 32 + dc * 8) = v;
    }
  } else {
    // V: stage transposed [c=128][t=128], row stride 136 u16; 4 t's per lane are contiguous
#pragma unroll
    for (int nt = 0; nt < 4; ++nt) {
      float bv = bias[ntile * 128 + wn + nt * 16 + il];
      int cl = wn + nt * 16 + il;
#pragma unroll
      for (int mt = 0; mt < 4; ++mt) {
        int T0 = wm + mt * 16 + ch * 4;
        ushort4 p;
        p.x = f2bf(acc[mt][nt][0] + bv);
        p.y = f2bf(acc[mt][nt][1] + bv);
        p.z = f2bf(acc[mt][nt][2] + bv);
        p.w = f2bf(acc[mt][nt][3] + bv);
        *(ushort4*)(Ct + cl * 136 + T0) = p;
      }
    }
    __syncthreads();
    // store: FULL t coverage (R2 bug: only t<32 was written). tq covers all 8
    // t-chunks; consecutive lanes -> contiguous 128B global runs.
    int wl = tid >> 7, dd = (tid >> 3) & 15, tq = tid & 7;
#pragma unroll
    for (int it = 0; it < 8; ++it) {
      int hl = it & 3, dh = it >> 2;
      int d = dh * 16 + dd;
      uint4 v = *(const uint4*)(smem + (hl * 32 + d) * 272 + wl * 128 + tq * 16);
      *(uint4*)(dst + ((gw0 + wl) * 16 + h0 + hl) * 2048 + d * 64 + tq * 8) = v;
    }
  }
}

// ---------------- kernel 4: attention, one block = (window, head)
__global__ __launch_bounds__(256) void attn(const u16* __restrict__ QKV,
                                            const float* __restrict__ btab,
                                            float* __restrict__ out) {
  __shared__ __attribute__((aligned(16))) u16 Pl[64 * 88];
  __shared__ float sbias[225];

  int bid = blockIdx.x;
  int w = bid >> 4, h = bid & 15;
  int tid = threadIdx.x;
  if (tid < 225) sbias[tid] = btab[tid * 16 + h];

  int lane = tid & 63, wv = tid >> 6;
  int il = lane & 15, ch = lane >> 4;
  const u16* Qb = QKV + (w * 16 + h) * 2048;
  const u16* Kb = Qb + SECSZ;
  const u16* Vt = Qb + 2 * (size_t)SECSZ;

  // S = Q K^T (Q already scaled); contiguous 16B frag loads
  bf16x8 aq = *(const bf16x8*)(Qb + (wv * 16 + il) * 32 + ch * 8);
  floatx4 zacc = {0.f, 0.f, 0.f, 0.f};
  floatx4 s[4];
#pragma unroll
  for (int jt = 0; jt < 4; ++jt) {
    bf16x8 bk = *(const bf16x8*)(Kb + (jt * 16 + il) * 32 + ch * 8);
    s[jt] = __builtin_amdgcn_mfma_f32_16x16x32_bf16(aq, bk, zacc, 0, 0, 0);
  }

  __syncthreads();   // sbias visible

  int winidx = w & 63;
  int wy = winidx >> 3, wx = winidx & 7;
  float val[4][4];
#pragma unroll
  for (int r = 0; r < 4; ++r) {
    int i = wv * 16 + ch * 4 + r;
    int ty = i >> 3, tx = i & 7;
    int ry = (wy == 7) ? (ty < 4 ? 1 : 2) : 0;
    int rx = (wx == 7) ? (tx < 4 ? 1 : 2) : 0;
    int li = ry * 3 + rx;
#pragma unroll
    for (int jt = 0; jt < 4; ++jt) {
      int j = jt * 16 + il;
      int sy = j >> 3, sx = j & 7;
      int rjy = (wy == 7) ? (sy < 4 ? 1 : 2) : 0;
      int rjx = (wx == 7) ? (sx < 4 ? 1 : 2) : 0;
      float v = s[jt][r] + sbias[(ty - sy + 7) * 15 + (tx - sx + 7)];
      if (li != (rjy * 3 + rjx)) v -= 100.0f;
      val[r][jt] = v;
    }
  }

#pragma unroll
  for (int r = 0; r < 4; ++r) {
    float m = fmaxf(fmaxf(val[r][0], val[r][1]), fmaxf(val[r][2], val[r][3]));
    m = fmaxf(m, __shfl_xor(m, 1, 64));
    m = fmaxf(m, __shfl_xor(m, 2, 64));
    m = fmaxf(m, __shfl_xor(m, 4, 64));
    m = fmaxf(m, __shfl_xor(m, 8, 64));
    float sum = 0.f;
#pragma unroll
    for (int jt = 0; jt < 4; ++jt) { val[r][jt] = __expf(val[r][jt] - m); sum += val[r][jt]; }
    sum += __shfl_xor(sum, 1, 64);
    sum += __shfl_xor(sum, 2, 64);
    sum += __shfl_xor(sum, 4, 64);
    sum += __shfl_xor(sum, 8, 64);
    float inv = 1.0f / sum;
    int i = wv * 16 + ch * 4 + r;
#pragma unroll
    for (int jt = 0; jt < 4; ++jt)
      Pl[i * 88 + jt * 16 + il] = f2bf(val[r][jt] * inv);
  }

  __syncthreads();   // P visible

  // O = P V : V^T frags straight from global ([d][t] layout)
  floatx4 o0 = zacc, o1 = zacc;
#pragma unroll
  for (int kk = 0; kk < 2; ++kk) {
    bf16x8 ap  = *(const bf16x8*)((const u16*)Pl + (wv * 16 + il) * 88 + kk * 32 + ch * 8);
    bf16x8 bv0 = *(const bf16x8*)(Vt + il * 64 + kk * 32 + ch * 8);
    bf16x8 bv1 = *(const bf16x8*)(Vt + (16 + il) * 64 + kk * 32 + ch * 8);
    o0 = __builtin_amdgcn_mfma_f32_16x16x32_bf16(ap, bv0, o0, 0, 0, 0);
    o1 = __builtin_amdgcn_mfma_f32_16x16x32_bf16(ap, bv1, o1, 0, 0, 0);
  }

  int img = w >> 6;
#pragma unroll
  for (int r = 0; r < 4; ++r) {
    int i = wv * 16 + ch * 4 + r;
    int ty = i >> 3, tx = i & 7;
    int y = wy * 8 + ty, xp = wx * 8 + tx;
    float* op = out + ((img * 64 + y) * 64 + xp) * 512 + h * 32;
    op[il] = o0[r];
    op[16 + il] = o1[r];
  }
}

extern "C" void kernel_launch(void* const* d_in, const int* in_sizes, int n_in,
                              void* d_out, int out_size, void* d_ws, size_t ws_size,
                              hipStream_t stream) {
  const float* x      = (const float*)d_in[0];
  const float* qkv_w  = (const float*)d_in[1];
  const float* qkv_b  = (const float*)d_in[2];
  const float* btab   = (const float*)d_in[3];
  float* out = (float*)d_out;

  char* ws = (char*)d_ws;
  u16* A   = (u16*)ws;                                              // 32 MB
  u16* Wb  = (u16*)(ws + (size_t)MTOK * KDIM * 2);                  // 1.5 MB
  u16* QKV = (u16*)(ws + (size_t)MTOK * KDIM * 2 + (size_t)NQKV * KDIM * 2);  // 96 MB (Q|K|V sections)

  convert_x<<<dim3(MTOK * KDIM / 1024), dim3(256), 0, stream>>>(x, A);
  convert_w<<<dim3(NQKV * KDIM / 1024), dim3(256), 0, stream>>>(qkv_w, Wb);
  gemm_qkv<<<dim3(3072), dim3(256), 0, stream>>>(A, Wb, qkv_b, QKV);
  attn<<<dim3(NWIN * N_HEAD), dim3(256), 0, stream>>>(QKV, btab, out);
}

// Round 4
// 227.227 us; speedup vs baseline: 1.0646x; 1.0546x over previous
//
#include <hip/hip_runtime.h>
#include <stdint.h>

typedef unsigned short u16;
typedef __attribute__((ext_vector_type(4))) float floatx4;
typedef __attribute__((ext_vector_type(8))) short bf16x8;

#define MTOK   32768   // 512 windows * 64 tokens
#define KDIM   512
#define NQKV   1536
#define NWIN   512
#define N_HEAD 16
#define SECSZ  (512 * 16 * 2048)   // u16 elems per Q/K/V section (32 MB)
#define QK_SCALE 0.17677669529663687f  // 32^-0.5

__device__ __forceinline__ u16 f2bf(float f) {
  union { float f; unsigned u; } v; v.f = f;
  unsigned r = v.u + 0x7fffu + ((v.u >> 16) & 1u);
  return (u16)(r >> 16);
}

__device__ __forceinline__ void load_lds16(const void* g, void* l) {
  __builtin_amdgcn_global_load_lds((const __attribute__((address_space(1))) void*)g,
                                   (__attribute__((address_space(3))) void*)l,
                                   16, 0, 0);
}

// ---------------- kernel 1: fused converts
// blocks [0,768): qkv_w fp32->bf16; blocks [768,17152): x -> A window-ordered bf16
__global__ __launch_bounds__(256) void convert_xw(const float* __restrict__ x,
                                                  const float* __restrict__ wsrc,
                                                  u16* __restrict__ A,
                                                  u16* __restrict__ Wb) {
  int b = blockIdx.x;
  if (b < 768) {
    int e = (b * 256 + threadIdx.x) * 4;
    const float4 v = *(const float4*)(wsrc + e);
    ushort4 o;
    o.x = f2bf(v.x); o.y = f2bf(v.y); o.z = f2bf(v.z); o.w = f2bf(v.w);
    *(ushort4*)(Wb + e) = o;
  } else {
    int idx = (b - 768) * 256 + threadIdx.x;
    int e = idx * 4;
    int c = e & 511;
    int tg = e >> 9;
    int w = tg >> 6, t = tg & 63;
    int img = w >> 6, wy = (w >> 3) & 7, wx = w & 7;
    int ty = t >> 3, tx = t & 7;
    int y = wy * 8 + ty, xp = wx * 8 + tx;
    const float4 v = *(const float4*)(x + (((img * 64 + y) * 64 + xp) * 512 + c));
    ushort4 o;
    o.x = f2bf(v.x); o.y = f2bf(v.y); o.z = f2bf(v.z); o.w = f2bf(v.w);
    *(ushort4*)(A + e) = o;
  }
}

// ---------------- kernel 2: QKV GEMM, bias fused, Q pre-scaled, V transposed
// out layouts (bf16): Q/K: [w][h][t=64][d=32]  V: [w][h][d=32][t=64]
// Epilogue in TWO 64-token passes through an 18.4 KB buffer (keeps occupancy:
// R3's 34.8 KB single-pass buffer dropped Occupancy 30%->20% and cost +9 us).
__global__ __launch_bounds__(256, 4) void gemm_qkv(const u16* __restrict__ A,
                                                   const u16* __restrict__ Wb,
                                                   const float* __restrict__ bias,
                                                   u16* __restrict__ QKV) {
  __shared__ __attribute__((aligned(16))) char smem[18432];
  u16* Ct = (u16*)smem;

  int b = blockIdx.x;
  int xcd = b & 7, slot = b >> 3;
  int mtile = (slot / 12) * 8 + xcd;   // [0,256)
  int ntile = slot % 12;               // [0,12)

  int tid = threadIdx.x;
  int wv = tid >> 6, lane = tid & 63;
  int il = lane & 15, ch = lane >> 4;
  int wm = (wv & 1) * 64, wn = (wv >> 1) * 64;

  floatx4 acc[4][4];
  floatx4 zacc = {0.f, 0.f, 0.f, 0.f};
#pragma unroll
  for (int m = 0; m < 4; ++m)
#pragma unroll
    for (int n = 0; n < 4; ++n) acc[m][n] = zacc;

  int row0 = tid >> 2;
  int ch4 = (tid & 3) ^ (row0 & 3);    // staging swizzle (bank-floor-equivalent, kept)
  const u16* Abase = A + (mtile * 128 + row0) * KDIM + ch4 * 8;
  const u16* Bbase = Wb + (ntile * 128 + row0) * KDIM + ch4 * 8;
  char* lAb = smem;
  char* lBb = smem + 8192;
  char* lA0 = lAb + wv * 1024;
  char* lA1 = lAb + 4096 + wv * 1024;
  char* lB0 = lBb + wv * 1024;
  char* lB1 = lBb + 4096 + wv * 1024;

  int sw = il & 3;
  for (int kb = 0; kb < KDIM; kb += 32) {
    __syncthreads();
    load_lds16(Abase + kb, lA0);
    load_lds16(Abase + kb + 64 * KDIM, lA1);
    load_lds16(Bbase + kb, lB0);
    load_lds16(Bbase + kb + 64 * KDIM, lB1);
    __syncthreads();

    bf16x8 af[4], bfr[4];
#pragma unroll
    for (int mt = 0; mt < 4; ++mt)
      af[mt] = *(const bf16x8*)(lAb + (wm + mt * 16 + il) * 64 + (ch ^ sw) * 16);
#pragma unroll
    for (int nt = 0; nt < 4; ++nt)
      bfr[nt] = *(const bf16x8*)(lBb + (wn + nt * 16 + il) * 64 + (ch ^ sw) * 16);
#pragma unroll
    for (int mt = 0; mt < 4; ++mt)
#pragma unroll
      for (int nt = 0; nt < 4; ++nt)
        acc[mt][nt] = __builtin_amdgcn_mfma_f32_16x16x32_bf16(af[mt], bfr[nt], acc[mt][nt], 0, 0, 0);
  }

  __syncthreads();   // K-loop LDS reads done before smem reuse

  // epilogue: C/D layout col=lane&15, row=(lane>>4)*4+reg
  int sec = ntile >> 2;              // 0=Q 1=K 2=V
  int h0 = (ntile & 3) * 4;          // 4 heads per block
  int gw0 = mtile * 2;               // 2 windows per block
  u16* dst = QKV + (size_t)sec * SECSZ;
  float sc = (sec == 0) ? QK_SCALE : 1.0f;

  for (int p = 0; p < 2; ++p) {      // pass p == window gw0+p (tokens p*64..p*64+63)
    if ((wv & 1) == p) {
      if (sec < 2) {
        // Ct[t_local=64][c=128], row stride 136 u16 (272B, 16*17 aligned)
#pragma unroll
        for (int nt = 0; nt < 4; ++nt) {
          float bv = bias[ntile * 128 + wn + nt * 16 + il];
          int cl = wn + nt * 16 + il;
#pragma unroll
          for (int mt = 0; mt < 4; ++mt) {
            int lr = mt * 16 + ch * 4;
#pragma unroll
            for (int r = 0; r < 4; ++r)
              Ct[(lr + r) * 136 + cl] = f2bf((acc[mt][nt][r] + bv) * sc);
          }
        }
      } else {
        // V transposed: Ct[c=128][t_local=64], row stride 72 u16 (144B, 16*9 aligned)
#pragma unroll
        for (int nt = 0; nt < 4; ++nt) {
          float bv = bias[ntile * 128 + wn + nt * 16 + il];
          int cl = wn + nt * 16 + il;
#pragma unroll
          for (int mt = 0; mt < 4; ++mt) {
            int lr = mt * 16 + ch * 4;
            ushort4 pk;
            pk.x = f2bf(acc[mt][nt][0] + bv);
            pk.y = f2bf(acc[mt][nt][1] + bv);
            pk.z = f2bf(acc[mt][nt][2] + bv);
            pk.w = f2bf(acc[mt][nt][3] + bv);
            *(ushort4*)(Ct + cl * 72 + lr) = pk;
          }
        }
      }
    }
    __syncthreads();

    if (sec < 2) {
      int tl = tid >> 2, dc = tid & 3;
#pragma unroll
      for (int hl = 0; hl < 4; ++hl) {
        uint4 v = *(const uint4*)(smem + tl * 272 + hl * 64 + dc * 16);
        *(uint4*)(dst + ((gw0 + p) * 16 + h0 + hl) * 2048 + tl * 32 + dc * 8) = v;
      }
    } else {
      int c0 = tid >> 3, tq = tid & 7;   // c0: d in [0,32), tq: t-chunk
#pragma unroll
      for (int hl = 0; hl < 4; ++hl) {
        uint4 v = *(const uint4*)(smem + (hl * 32 + c0) * 144 + tq * 16);
        *(uint4*)(dst + ((gw0 + p) * 16 + h0 + hl) * 2048 + c0 * 64 + tq * 8) = v;
      }
    }
    __syncthreads();   // buffer free for next pass's writers
  }
}

// ---------------- kernel 3: attention, one block = (window, head)
__global__ __launch_bounds__(256) void attn(const u16* __restrict__ QKV,
                                            const float* __restrict__ btab,
                                            float* __restrict__ out) {
  __shared__ __attribute__((aligned(16))) u16 Pl[64 * 88];
  __shared__ float sbias[225];

  int bid = blockIdx.x;
  int w = bid >> 4, h = bid & 15;
  int tid = threadIdx.x;
  if (tid < 225) sbias[tid] = btab[tid * 16 + h];

  int lane = tid & 63, wv = tid >> 6;
  int il = lane & 15, ch = lane >> 4;
  const u16* Qb = QKV + (w * 16 + h) * 2048;
  const u16* Kb = Qb + SECSZ;
  const u16* Vt = Qb + 2 * (size_t)SECSZ;

  // S = Q K^T (Q already scaled); contiguous 16B frag loads
  bf16x8 aq = *(const bf16x8*)(Qb + (wv * 16 + il) * 32 + ch * 8);
  floatx4 zacc = {0.f, 0.f, 0.f, 0.f};
  floatx4 s[4];
#pragma unroll
  for (int jt = 0; jt < 4; ++jt) {
    bf16x8 bk = *(const bf16x8*)(Kb + (jt * 16 + il) * 32 + ch * 8);
    s[jt] = __builtin_amdgcn_mfma_f32_16x16x32_bf16(aq, bk, zacc, 0, 0, 0);
  }

  __syncthreads();   // sbias visible

  int winidx = w & 63;
  int wy = winidx >> 3, wx = winidx & 7;
  float val[4][4];
#pragma unroll
  for (int r = 0; r < 4; ++r) {
    int i = wv * 16 + ch * 4 + r;
    int ty = i >> 3, tx = i & 7;
    int ry = (wy == 7) ? (ty < 4 ? 1 : 2) : 0;
    int rx = (wx == 7) ? (tx < 4 ? 1 : 2) : 0;
    int li = ry * 3 + rx;
#pragma unroll
    for (int jt = 0; jt < 4; ++jt) {
      int j = jt * 16 + il;
      int sy = j >> 3, sx = j & 7;
      int rjy = (wy == 7) ? (sy < 4 ? 1 : 2) : 0;
      int rjx = (wx == 7) ? (sx < 4 ? 1 : 2) : 0;
      float v = s[jt][r] + sbias[(ty - sy + 7) * 15 + (tx - sx + 7)];
      if (li != (rjy * 3 + rjx)) v -= 100.0f;
      val[r][jt] = v;
    }
  }

#pragma unroll
  for (int r = 0; r < 4; ++r) {
    float m = fmaxf(fmaxf(val[r][0], val[r][1]), fmaxf(val[r][2], val[r][3]));
    m = fmaxf(m, __shfl_xor(m, 1, 64));
    m = fmaxf(m, __shfl_xor(m, 2, 64));
    m = fmaxf(m, __shfl_xor(m, 4, 64));
    m = fmaxf(m, __shfl_xor(m, 8, 64));
    float sum = 0.f;
#pragma unroll
    for (int jt = 0; jt < 4; ++jt) { val[r][jt] = __expf(val[r][jt] - m); sum += val[r][jt]; }
    sum += __shfl_xor(sum, 1, 64);
    sum += __shfl_xor(sum, 2, 64);
    sum += __shfl_xor(sum, 4, 64);
    sum += __shfl_xor(sum, 8, 64);
    float inv = 1.0f / sum;
    int i = wv * 16 + ch * 4 + r;
#pragma unroll
    for (int jt = 0; jt < 4; ++jt)
      Pl[i * 88 + jt * 16 + il] = f2bf(val[r][jt] * inv);
  }

  __syncthreads();   // P visible

  // O = P V : V^T frags straight from global ([d][t] layout)
  floatx4 o0 = zacc, o1 = zacc;
#pragma unroll
  for (int kk = 0; kk < 2; ++kk) {
    bf16x8 ap  = *(const bf16x8*)((const u16*)Pl + (wv * 16 + il) * 88 + kk * 32 + ch * 8);
    bf16x8 bv0 = *(const bf16x8*)(Vt + il * 64 + kk * 32 + ch * 8);
    bf16x8 bv1 = *(const bf16x8*)(Vt + (16 + il) * 64 + kk * 32 + ch * 8);
    o0 = __builtin_amdgcn_mfma_f32_16x16x32_bf16(ap, bv0, o0, 0, 0, 0);
    o1 = __builtin_amdgcn_mfma_f32_16x16x32_bf16(ap, bv1, o1, 0, 0, 0);
  }

  int img = w >> 6;
#pragma unroll
  for (int r = 0; r < 4; ++r) {
    int i = wv * 16 + ch * 4 + r;
    int ty = i >> 3, tx = i & 7;
    int y = wy * 8 + ty, xp = wx * 8 + tx;
    float* op = out + ((img * 64 + y) * 64 + xp) * 512 + h * 32;
    op[il] = o0[r];
    op[16 + il] = o1[r];
  }
}

extern "C" void kernel_launch(void* const* d_in, const int* in_sizes, int n_in,
                              void* d_out, int out_size, void* d_ws, size_t ws_size,
                              hipStream_t stream) {
  const float* x      = (const float*)d_in[0];
  const float* qkv_w  = (const float*)d_in[1];
  const float* qkv_b  = (const float*)d_in[2];
  const float* btab   = (const float*)d_in[3];
  float* out = (float*)d_out;

  char* ws = (char*)d_ws;
  u16* A   = (u16*)ws;                                              // 32 MB
  u16* Wb  = (u16*)(ws + (size_t)MTOK * KDIM * 2);                  // 1.5 MB
  u16* QKV = (u16*)(ws + (size_t)MTOK * KDIM * 2 + (size_t)NQKV * KDIM * 2);  // 96 MB (Q|K|V sections)

  convert_xw<<<dim3(17152), dim3(256), 0, stream>>>(x, qkv_w, A, Wb);
  gemm_qkv<<<dim3(3072), dim3(256), 0, stream>>>(A, Wb, qkv_b, QKV);
  attn<<<dim3(NWIN * N_HEAD), dim3(256), 0, stream>>>(QKV, btab, out);
}